// Round 1
// 71.551 us; speedup vs baseline: 1.1691x; 1.1691x over previous
//
#include <hip/hip_runtime.h>

#define B 512
#define D 256
#define NCLS 10
#define MARGIN 0.2f
#define THREADS 1024
#define NWAVES (THREADS / 64)   // 16 waves -> 4 waves/SIMD (was 1)
#define ROWS 2
#define NBLOCKS (B / ROWS)      // 256 blocks = 1/CU
#define DT 32                   // D-slice width per tile
#define NDT (D / DT)            // 8 tiles
#define JS 36                   // padded row stride (floats): 144B rows -> 16B-aligned
                                // float4 quad-stride 9 (odd) -> conflict-free b128 r/w

// v2: 1024 threads (4 waves/SIMD latency hiding), row-major padded LDS slice
// (vectorized ds_write_b128 staging -- no 4x scalar transpose writes), one sim
// column per thread (j = t&511) with wave-uniform anchor row (r = t>>9),
// anchors via LDS float4 broadcast. Hinge phase for both rows runs in
// parallel across the two wave-halves; per-thread neg value hoisted out of
// the P-loop (1 LDS read instead of P).
//
// Conflict analysis (32 banks, quad granularity for b128):
//  - stage write: 8 consecutive lanes = same row, m=0..7 -> quads 4(r+m)%32
//    all distinct within the group -> conflict-free in natural order.
//  - col read: lane t reads quad (9t+e4)%8 -> 8 consecutive lanes distinct.
//  - anchor read: wave-uniform address -> broadcast (free).
__global__ __launch_bounds__(THREADS) void fused_loss_kernel(
    const float* __restrict__ F, const int* __restrict__ labels,
    float* __restrict__ out)
{
    __shared__ float ldsR[B * JS];          // 72 KB row-major F slice (padded)
    __shared__ float fi[ROWS][D];           // anchor rows
    __shared__ float simrow[ROWS][B];
    __shared__ int   lbl[B];
    __shared__ float pos_vals[ROWS][B];
    __shared__ float neg_vals[ROWS][B];
    __shared__ int   cnt[ROWS][2];
    __shared__ int   hist[NCLS];
    __shared__ float wred[NWAVES];
    __shared__ int   vred[NWAVES];

    const int t    = threadIdx.x;
    const int lane = t & 63;
    const int w    = t >> 6;
    const int i0   = blockIdx.x * ROWS;
    const int r    = t >> 9;                // wave-uniform anchor-row select
    const int j    = t & (B - 1);           // sim column owned by this thread

    // stage labels, anchor rows (coalesced float4), zero histogram + counters
    if (t < B)    lbl[t] = labels[t];
    if (t < NCLS) hist[t] = 0;
    if (t < (ROWS * D) / 4)
        ((float4*)fi)[t] = ((const float4*)(F + (size_t)i0 * D))[t];
    if (t < ROWS * 2) ((int*)cnt)[t] = 0;
    __syncthreads();

    // label histogram (10 bins, LDS atomics); consumed after the sim phase
    if (t < B) atomicAdd(&hist[lbl[t]], 1);

    // ---- sim phase: 8 D-tiles, register accumulation (1 col x 1 row) ----
    float acc = 0.f;
    const float4* Fv   = (const float4*)F;
    const float*  base = &ldsR[j * JS];
    const float*  fr   = fi[r];
    for (int tile = 0; tile < NDT; ++tile) {
        const int dt4 = tile * (DT / 4);
        // stage: 512 rows x 8 float4 = 4096 float4; 4 per thread, b128 writes.
#pragma unroll
        for (int k = 0; k < (B * DT / 4) / THREADS; ++k) {   // 4
            const int g   = t + THREADS * k;
            const int row = g >> 3;
            const int m   = g & 7;
            *(float4*)&ldsR[row * JS + 4 * m] = Fv[row * (D / 4) + dt4 + m];
        }
        __syncthreads();
        const int dt = tile * DT;
#pragma unroll
        for (int e4 = 0; e4 < DT / 4; ++e4) {
            const float4 a = *(const float4*)&fr[dt + 4 * e4];   // broadcast
            const float4 x = *(const float4*)&base[4 * e4];      // conflict-free
            acc = fmaf(a.x, x.x, acc);
            acc = fmaf(a.y, x.y, acc);
            acc = fmaf(a.z, x.z, acc);
            acc = fmaf(a.w, x.w, acc);
        }
        __syncthreads();  // before next tile's staging overwrites ldsR
    }
    simrow[r][j] = acc;
    __syncthreads();

    // num_valid contribution: row j valid iff 2 <= c[l_j] <= B-1
    {
        bool valid = false;
        if (t < B) { const int c = hist[lbl[t]]; valid = (c >= 2) && (c <= B - 1); }
        const unsigned long long mv = __ballot(valid);
        if (lane == 0) vred[w] = __popcll(mv);
    }

    // ---- hinge phase: both rows concurrently (wave-half per row) ----
    const int i_r = i0 + r;
    const int li  = lbl[i_r];
    {
        const bool active = (j != i_r);
        const bool ispos  = active && (lbl[j] == li);
        const bool isneg  = active && (lbl[j] != li);
        const unsigned long long mp = __ballot(ispos);
        const unsigned long long mn = __ballot(isneg);
        int basep = 0, basen = 0;
        if (lane == 0) {
            basep = atomicAdd(&cnt[r][0], __popcll(mp));
            basen = atomicAdd(&cnt[r][1], __popcll(mn));
        }
        basep = __shfl(basep, 0, 64);
        basen = __shfl(basen, 0, 64);
        const unsigned long long below = (1ull << lane) - 1ull;
        const float sv = simrow[r][j];
        if (ispos) pos_vals[r][basep + __popcll(mp & below)] = sv;
        if (isneg) neg_vals[r][basen + __popcll(mn & below)] = sv;
    }
    __syncthreads();

    const int P = cnt[r][0], N = cnt[r][1];
    // thread owns one neg value (N <= 511 < 512); hoisted out of the P-loop.
    const float nv_t = (j < N) ? neg_vals[r][j] : -1e30f;
    float local = 0.f;
    for (int pi = 0; pi < P; ++pi) {
        const float v = nv_t - (pos_vals[r][pi] - MARGIN);  // margin + s_n - s_p
        local += (v > 0.f) ? v : 0.f;
    }

    // block reduction: wave64 shuffle, then across 16 waves via LDS
#pragma unroll
    for (int off = 32; off > 0; off >>= 1)
        local += __shfl_down(local, off, 64);
    if (lane == 0) wred[w] = local;
    __syncthreads();
    if (t == 0) {
        float s = 0.f;
        int   nv = 0;
#pragma unroll
        for (int k = 0; k < NWAVES; ++k) { s += wred[k]; nv += vred[k]; }
        const int   clast = hist[lbl[B - 1]];
        const float denom = (float)nv * (float)(clast - 1) * (float)(B - clast);
        atomicAdd(out, (denom > 0.f) ? s / denom : 0.f);
    }
}

extern "C" void kernel_launch(void* const* d_in, const int* in_sizes, int n_in,
                              void* d_out, int out_size, void* d_ws, size_t ws_size,
                              hipStream_t stream) {
    const float* F      = (const float*)d_in[0];   // [512, 256] fp32
    const int*   labels = (const int*)d_in[1];     // [512] int32
    float* out = (float*)d_out;
    (void)d_ws; (void)ws_size;

    fused_loss_kernel<<<NBLOCKS, THREADS, 0, stream>>>(F, labels, out);
}